// Round 1
// baseline (86.467 us; speedup 1.0000x reference)
//
#include <hip/hip_runtime.h>
#include <hip/hip_bf16.h>

typedef __attribute__((ext_vector_type(8))) short short8;
typedef __attribute__((ext_vector_type(4))) float f32x4;

__device__ __forceinline__ short f2bf(float f) {
  union { float f; unsigned u; } x; x.f = f;
  unsigned r = (x.u + 0x7FFFu + ((x.u >> 16) & 1u)) >> 16;  // RNE
  return (short)r;
}

// One workgroup (256 threads / 4 waves) per (n, h, block).
// Keys per block: 64 global | 128 sparse-left | 128 sparse-right | 384 local = 704 = 22 tiles of 32.
__global__ __launch_bounds__(256) void lsg_attn_kernel(
    const float* __restrict__ q_,  const float* __restrict__ k_,
    const float* __restrict__ v_,  const float* __restrict__ amask,
    const float* __restrict__ sk,  const float* __restrict__ sv,
    const float* __restrict__ smk, const float* __restrict__ gk,
    const float* __restrict__ gv,  const float* __restrict__ gmk,
    float* __restrict__ out)
{
  constexpr int T = 4096, D = 64, TS = 1024;
  constexpr float NEGF = -3.402823466e38f;

  __shared__ __align__(16) short k_lds[32][72];     // [key][d], padded stride
  __shared__ __align__(16) short v_lds[64][40];     // transposed: [d][key], padded
  __shared__ __align__(16) short p_lds[4][32][40];  // per-wave P bounce [q][key]
  __shared__ float m_lds[32];                       // mask value per key

  const int bid  = blockIdx.x;
  const int b    = bid & 31;        // block index within sequence (32 blocks)
  const int nh   = bid >> 5;        // n*12 + h
  const int n_   = nh / 12;
  const int tid  = threadIdx.x;
  const int wid  = tid >> 6;
  const int lane = tid & 63;
  const int c    = lane & 15;       // MFMA col / row-within-16
  const int g    = lane >> 4;       // MFMA lane group 0..3

  const float* qb  = q_ + ((size_t)nh * T + (size_t)b * 128) * D;
  const float* kb  = k_ + (size_t)nh * T * D;
  const float* vb  = v_ + (size_t)nh * T * D;
  const float* skb = sk + (size_t)nh * TS * D;
  const float* svb = sv + (size_t)nh * TS * D;
  const float* gkb = gk + (size_t)nh * 64 * D;
  const float* gvb = gv + (size_t)nh * 64 * D;
  const float* am  = amask + (size_t)n_ * T;
  const float* sm  = smk   + (size_t)n_ * TS;
  const float* gm  = gmk   + (size_t)n_ * 64;

  // ---- Q fragments (bf16) for this wave's 32 queries, direct from global ----
  // A-frag layout: row = lane&15, k = (lane>>4)*8 + j
  short8 qa[2][2];
#pragma unroll
  for (int mt = 0; mt < 2; ++mt)
#pragma unroll
    for (int kc = 0; kc < 2; ++kc) {
      const float* qp = qb + (size_t)(wid * 32 + mt * 16 + c) * D + kc * 32 + g * 8;
      short8 t;
#pragma unroll
      for (int j = 0; j < 8; ++j) t[j] = f2bf(qp[j]);
      qa[mt][kc] = t;
    }

  f32x4 acc[2][4];
#pragma unroll
  for (int mt = 0; mt < 2; ++mt)
#pragma unroll
    for (int dd = 0; dd < 4; ++dd) acc[mt][dd] = f32x4{0.f, 0.f, 0.f, 0.f};
  float mrun[2][4], lrun[2][4];
#pragma unroll
  for (int mt = 0; mt < 2; ++mt)
#pragma unroll
    for (int j = 0; j < 4; ++j) { mrun[mt][j] = NEGF; lrun[mt][j] = 0.f; }

  const int key_local = tid >> 3;  // 0..31: key within tile
  const int seg = tid & 7;         // 8-float segment of d
  const int d0  = seg * 8;

  for (int tile = 0; tile < 22; ++tile) {
    __syncthreads();  // previous tile's compute done -> safe to restage
    // ---- stage K, V(transposed), mask into LDS ----
    {
      const int kk = tile * 32 + key_local;
      const float* ksrc; const float* vsrc; float mval; bool valid;
      if (kk < 64) {                       // global
        ksrc = gkb + kk * D; vsrc = gvb + kk * D; mval = gm[kk]; valid = true;
      } else if (kk < 320) {               // sparse (two chunks)
        int s = b * 32 - 160 + (kk - 64) + ((kk >= 192) ? 96 : 0);
        valid = (s >= 0) && (s < TS);
        int sc2 = valid ? s : 0;
        ksrc = skb + sc2 * D; vsrc = svb + sc2 * D;
        mval = valid ? sm[sc2] : NEGF;
      } else {                             // local: tokens [b*128-128, b*128+256)
        int tt = b * 128 - 128 + (kk - 320);
        valid = (tt >= 0) && (tt < T);
        int tc = valid ? tt : 0;
        ksrc = kb + tc * D; vsrc = vb + tc * D;
        mval = valid ? am[tc] : NEGF;
      }
      short8 k8; short v8[8];
      if (valid) {
#pragma unroll
        for (int j = 0; j < 8; ++j) { k8[j] = f2bf(ksrc[d0 + j]); v8[j] = f2bf(vsrc[d0 + j]); }
      } else {
#pragma unroll
        for (int j = 0; j < 8; ++j) { k8[j] = 0; v8[j] = 0; }
      }
      *(short8*)(&k_lds[key_local][d0]) = k8;          // 16B aligned (144B row stride)
#pragma unroll
      for (int j = 0; j < 8; ++j) v_lds[d0 + j][key_local] = v8[j];
      if (seg == 0) m_lds[key_local] = mval;
    }
    __syncthreads();

    // ---- QK^T: S[32q x 32k], D-layout ----
    short8 bk[2][2];
#pragma unroll
    for (int kt = 0; kt < 2; ++kt)
#pragma unroll
      for (int kc = 0; kc < 2; ++kc)
        bk[kt][kc] = *(const short8*)(&k_lds[kt * 16 + c][kc * 32 + g * 8]);

    f32x4 s_[2][2];
#pragma unroll
    for (int mt = 0; mt < 2; ++mt)
#pragma unroll
      for (int kt = 0; kt < 2; ++kt) {
        f32x4 z = f32x4{0.f, 0.f, 0.f, 0.f};
        z = __builtin_amdgcn_mfma_f32_16x16x32_bf16(qa[mt][0], bk[kt][0], z, 0, 0, 0);
        z = __builtin_amdgcn_mfma_f32_16x16x32_bf16(qa[mt][1], bk[kt][1], z, 0, 0, 0);
        s_[mt][kt] = z;
      }

    const float msk0 = m_lds[c];
    const float msk1 = m_lds[16 + c];

    // ---- online softmax (rows live in 16-lane groups; xor-reduce max) ----
#pragma unroll
    for (int mt = 0; mt < 2; ++mt) {
#pragma unroll
      for (int j = 0; j < 4; ++j) {
        float s0 = s_[mt][0][j] * 0.125f + msk0;   // 1/sqrt(64)
        float s1 = s_[mt][1][j] * 0.125f + msk1;
        float tv = fmaxf(s0, s1);
        tv = fmaxf(tv, __shfl_xor(tv, 1));
        tv = fmaxf(tv, __shfl_xor(tv, 2));
        tv = fmaxf(tv, __shfl_xor(tv, 4));
        tv = fmaxf(tv, __shfl_xor(tv, 8));
        float mold = mrun[mt][j];
        float mnew = fmaxf(mold, tv);
        float scale = __expf(mold - mnew);
        mrun[mt][j] = mnew;
        float p0 = __expf(s0 - mnew);
        float p1 = __expf(s1 - mnew);
        lrun[mt][j] = lrun[mt][j] * scale + p0 + p1;  // lane-partial; reduced at end
#pragma unroll
        for (int dd = 0; dd < 4; ++dd) acc[mt][dd][j] *= scale;
        p_lds[wid][mt * 16 + g * 4 + j][c]      = f2bf(p0);
        p_lds[wid][mt * 16 + g * 4 + j][16 + c] = f2bf(p1);
      }
    }
    __syncthreads();  // P visible (and keeps waves in step before restage)

    // ---- PV: acc += P(32x32) * V(32x64) ----
#pragma unroll
    for (int mt = 0; mt < 2; ++mt) {
      short8 pa = *(const short8*)(&p_lds[wid][mt * 16 + c][g * 8]);
#pragma unroll
      for (int dd = 0; dd < 4; ++dd) {
        short8 bv = *(const short8*)(&v_lds[dd * 16 + c][g * 8]);
        acc[mt][dd] = __builtin_amdgcn_mfma_f32_16x16x32_bf16(pa, bv, acc[mt][dd], 0, 0, 0);
      }
    }
  }

  // ---- epilogue: reduce l across the 16-lane group, normalize, store fp32 ----
  float* ob = out + ((size_t)nh * T + (size_t)b * 128 + (size_t)wid * 32) * D;
#pragma unroll
  for (int mt = 0; mt < 2; ++mt)
#pragma unroll
    for (int j = 0; j < 4; ++j) {
      float l = lrun[mt][j];
      l += __shfl_xor(l, 1);
      l += __shfl_xor(l, 2);
      l += __shfl_xor(l, 4);
      l += __shfl_xor(l, 8);
      float inv = 1.f / l;
      int row = mt * 16 + g * 4 + j;
#pragma unroll
      for (int dd = 0; dd < 4; ++dd)
        ob[(size_t)row * D + dd * 16 + c] = acc[mt][dd][j] * inv;
    }
}

extern "C" void kernel_launch(void* const* d_in, const int* in_sizes, int n_in,
                              void* d_out, int out_size, void* d_ws, size_t ws_size,
                              hipStream_t stream) {
  const float* q  = (const float*)d_in[0];
  const float* k  = (const float*)d_in[1];
  const float* v  = (const float*)d_in[2];
  const float* am = (const float*)d_in[3];
  const float* sk = (const float*)d_in[4];
  const float* sv = (const float*)d_in[5];
  const float* sm = (const float*)d_in[6];
  const float* gk = (const float*)d_in[7];
  const float* gv = (const float*)d_in[8];
  const float* gm = (const float*)d_in[9];
  float* out = (float*)d_out;

  dim3 grid(2 * 12 * 32);  // n * h * n_blocks
  dim3 blk(256);
  hipLaunchKernelGGL(lsg_attn_kernel, grid, blk, 0, stream,
                     q, k, v, am, sk, sv, sm, gk, gv, gm, out);
}

// Round 3
// 77.422 us; speedup vs baseline: 1.1168x; 1.1168x over previous
//
#include <hip/hip_runtime.h>
#include <hip/hip_bf16.h>

typedef __attribute__((ext_vector_type(8))) short short8;
typedef __attribute__((ext_vector_type(4))) float f32x4;

#define LOG2E 1.44269504f
#define SCL2  0.18033688f   // 0.125 * log2(e)
#define MNEG  -3.0e38f
#define MINIT -1.0e30f

__device__ __forceinline__ short f2bf(float f) {
  union { float f; unsigned u; } x; x.f = f;
  return (short)((x.u + 0x7FFFu + ((x.u >> 16) & 1u)) >> 16);  // RNE
}
__device__ __forceinline__ float exp2g(float x) {
  float r; asm("v_exp_f32 %0, %1" : "=v"(r) : "v"(x)); return r;
}
__device__ __forceinline__ unsigned cvt_pk_bf16(float lo, float hi) {
  unsigned r;
  asm("v_cvt_pk_bf16_f32 %0, %1, %2" : "=v"(r) : "v"(lo), "v"(hi));
  return r;
}

// ---------------- prepass: fp32 -> bf16 K with token padding ----------------
__global__ __launch_bounds__(256) void convk_kernel(
    const float* __restrict__ src, short* __restrict__ dst,
    int Tin, int pad, int total_chunks) {
  int cid = blockIdx.x * 256 + threadIdx.x;
  if (cid >= total_chunks) return;
  int Tpad = Tin + 2 * pad;
  int row = cid >> 3;
  int d0 = (cid & 7) * 8;
  int tok = row % Tpad;
  int nh = row / Tpad;
  int st = tok - pad;
  short8 o;
  if (st >= 0 && st < Tin) {
    const float4* sp = (const float4*)(src + ((size_t)nh * Tin + st) * 64 + d0);
    float4 f0 = sp[0], f1 = sp[1];
    o[0] = f2bf(f0.x); o[1] = f2bf(f0.y); o[2] = f2bf(f0.z); o[3] = f2bf(f0.w);
    o[4] = f2bf(f1.x); o[5] = f2bf(f1.y); o[6] = f2bf(f1.z); o[7] = f2bf(f1.w);
  } else {
#pragma unroll
    for (int j = 0; j < 8; ++j) o[j] = 0;
  }
  *(short8*)(dst + (size_t)row * 64 + d0) = o;
}

// ---------------- prepass: fp32 V -> bf16 V^T [nh][64][Tpad] ----------------
__global__ __launch_bounds__(256) void transv_kernel(
    const float* __restrict__ src, short* __restrict__ dst,
    int Tin, int pad, int tiles) {
  int tile = blockIdx.x % tiles;
  int nh = blockIdx.x / tiles;
  int Tpad = Tin + 2 * pad;
  int c0 = tile * 64;
  __shared__ short lt[64][72];
  int tid = threadIdx.x;
  int tok = tid >> 2;
  int dc = (tid & 3) * 16;
  int st = c0 + tok - pad;
  if (st >= 0 && st < Tin) {
    const float4* sp = (const float4*)(src + ((size_t)nh * Tin + st) * 64 + dc);
#pragma unroll
    for (int i = 0; i < 4; ++i) {
      float4 f = sp[i];
      lt[tok][dc + i * 4 + 0] = f2bf(f.x);
      lt[tok][dc + i * 4 + 1] = f2bf(f.y);
      lt[tok][dc + i * 4 + 2] = f2bf(f.z);
      lt[tok][dc + i * 4 + 3] = f2bf(f.w);
    }
  } else {
#pragma unroll
    for (int i = 0; i < 16; ++i) lt[tok][dc + i] = 0;
  }
  __syncthreads();
  int d = tid >> 2;
  int tc = (tid & 3) * 16;
  short8 o0, o1;
#pragma unroll
  for (int j = 0; j < 8; ++j) { o0[j] = lt[tc + j][d]; o1[j] = lt[tc + 8 + j][d]; }
  short* dp = dst + ((size_t)nh * 64 + d) * Tpad + c0 + tc;
  *(short8*)(dp) = o0;
  *(short8*)(dp + 8) = o1;
}

// ---------------- prepass: masks padded + pre-scaled by log2(e) -------------
__global__ __launch_bounds__(256) void maskk_kernel(
    const float* __restrict__ am, const float* __restrict__ sm,
    const float* __restrict__ gm,
    float* __restrict__ am2, float* __restrict__ sm2, float* __restrict__ gm2) {
  int i = blockIdx.x * 256 + threadIdx.x;
  if (i < 2 * 4352) {
    int n = i / 4352, r = i % 4352, s = r - 128;
    am2[i] = (s >= 0 && s < 4096) ? am[n * 4096 + s] * LOG2E : MNEG;
  } else if (i < 2 * 4352 + 2 * 1344) {
    int j = i - 2 * 4352;
    int n = j / 1344, r = j % 1344, s = r - 160;
    sm2[j] = (s >= 0 && s < 1024) ? sm[n * 1024 + s] * LOG2E : MNEG;
  } else if (i < 2 * 4352 + 2 * 1344 + 2 * 64) {
    int j = i - 2 * 4352 - 2 * 1344;
    gm2[j] = gm[j] * LOG2E;
  }
}

// ---------------- main attention kernel -------------------------------------
// One workgroup (4 waves) per (n,h,block). 11 tiles of 64 keys:
// tile 0: global(64) | tiles 1-4: sparse | tiles 5-10: local.
// K rows in LDS are key-interleaved: row r <- source key 4*(r&15)+(r>>4), so
// each lane's 4 P values (kt=0..3 at col c) are consecutive keys -> b64 store.
__global__ __launch_bounds__(256, 3) void lsg_attn2(
    const short* __restrict__ KL, const short* __restrict__ VTL,
    const short* __restrict__ KS, const short* __restrict__ VTS,
    const short* __restrict__ KG, const short* __restrict__ VTG,
    const float* __restrict__ AM2, const float* __restrict__ SM2,
    const float* __restrict__ GM2,
    const float* __restrict__ q_, float* __restrict__ out) {
  constexpr int TPL = 4352, TPS = 1344;
  __shared__ __align__(16) short k_lds[2][64][72];
  __shared__ __align__(16) short v_lds[2][64][72];
  __shared__ __align__(16) short p_lds[4][32][64];   // XOR-swizzled

  int bid = blockIdx.x;
  bid = (bid & 7) * 96 + (bid >> 3);        // XCD-contiguous logical ids
  const int b = bid & 31, nh = bid >> 5, n_ = nh / 12;
  const int tid = threadIdx.x;
  const int wid = tid >> 6, lane = tid & 63;
  const int c = lane & 15, g = lane >> 4;
  const int r = tid >> 2, ch = tid & 3;
  const int skey = 4 * (r & 15) + (r >> 4); // interleaved K source key for row r

  // ---- Q fragments ----
  const float* qb = q_ + ((size_t)nh * 4096 + (size_t)b * 128) * 64;
  short8 qa[2][2];
#pragma unroll
  for (int mt = 0; mt < 2; ++mt)
#pragma unroll
    for (int kc = 0; kc < 2; ++kc) {
      const float* qp = qb + (size_t)(wid * 32 + mt * 16 + c) * 64 + kc * 32 + g * 8;
      float4 f0 = *(const float4*)(qp);
      float4 f1 = *(const float4*)(qp + 4);
      short8 tq;
      tq[0] = f2bf(f0.x); tq[1] = f2bf(f0.y); tq[2] = f2bf(f0.z); tq[3] = f2bf(f0.w);
      tq[4] = f2bf(f1.x); tq[5] = f2bf(f1.y); tq[6] = f2bf(f1.z); tq[7] = f2bf(f1.w);
      qa[mt][kc] = tq;
    }

  f32x4 acc[2][4];
  float mrun[2][4], lrun[2][4];
#pragma unroll
  for (int mt = 0; mt < 2; ++mt)
#pragma unroll
    for (int dd = 0; dd < 4; ++dd) acc[mt][dd] = f32x4{0.f, 0.f, 0.f, 0.f};
#pragma unroll
  for (int mt = 0; mt < 2; ++mt)
#pragma unroll
    for (int j = 0; j < 4; ++j) { mrun[mt][j] = MINIT; lrun[mt][j] = 0.f; }

  auto src_for = [&](int t, const short*& kp, const short*& vp,
                     const float*& mp, int& stride) {
    if (t == 0) {
      kp = KG + (size_t)nh * (64 * 64);
      vp = VTG + (size_t)nh * (64 * 64);
      mp = GM2 + n_ * 64;
      stride = 64;
    } else if (t <= 4) {
      int r0 = b * 32 + (t - 1) * 64 + (t >= 3 ? 96 : 0);
      kp = KS + ((size_t)nh * TPS + r0) * 64;
      vp = VTS + (size_t)nh * (64 * TPS) + r0;
      mp = SM2 + n_ * TPS + r0;
      stride = TPS;
    } else {
      int r0 = b * 128 + (t - 5) * 64;
      kp = KL + ((size_t)nh * TPL + r0) * 64;
      vp = VTL + (size_t)nh * (64 * TPL) + r0;
      mp = AM2 + n_ * TPL + r0;
      stride = TPL;
    }
  };

  short8 kr0, kr1, vr0, vr1;
  float m_cur[4], m_nxt[4];
  char* pbase = (char*)&p_lds[wid][0][0];

  // ---- prologue: tile0 -> buf0, load tile1 regs, tile0 masks ----
  {
    const short* kp; const short* vp; const float* mp; int st;
    src_for(0, kp, vp, mp, st);
    kr0 = *(const short8*)(kp + skey * 64 + ch * 8);
    kr1 = *(const short8*)(kp + skey * 64 + ch * 8 + 32);
    vr0 = *(const short8*)(vp + (size_t)r * st + ch * 8);
    vr1 = *(const short8*)(vp + (size_t)r * st + ch * 8 + 32);
#pragma unroll
    for (int i = 0; i < 4; ++i) m_cur[i] = mp[4 * c + i];
    *(short8*)(&k_lds[0][r][ch * 8]) = kr0;
    *(short8*)(&k_lds[0][r][ch * 8 + 32]) = kr1;
    *(short8*)(&v_lds[0][r][ch * 8]) = vr0;
    *(short8*)(&v_lds[0][r][ch * 8 + 32]) = vr1;
    src_for(1, kp, vp, mp, st);
    kr0 = *(const short8*)(kp + skey * 64 + ch * 8);
    kr1 = *(const short8*)(kp + skey * 64 + ch * 8 + 32);
    vr0 = *(const short8*)(vp + (size_t)r * st + ch * 8);
    vr1 = *(const short8*)(vp + (size_t)r * st + ch * 8 + 32);
  }

  for (int t = 0; t < 11; ++t) {
    __syncthreads();
    const int cur = t & 1, nxt = cur ^ 1;
    if (t < 10) {   // write staged tile t+1
      *(short8*)(&k_lds[nxt][r][ch * 8]) = kr0;
      *(short8*)(&k_lds[nxt][r][ch * 8 + 32]) = kr1;
      *(short8*)(&v_lds[nxt][r][ch * 8]) = vr0;
      *(short8*)(&v_lds[nxt][r][ch * 8 + 32]) = vr1;
    }
    if (t < 9) {    // prefetch tile t+2 into regs
      const short* kp; const short* vp; const float* mp; int st;
      src_for(t + 2, kp, vp, mp, st);
      kr0 = *(const short8*)(kp + skey * 64 + ch * 8);
      kr1 = *(const short8*)(kp + skey * 64 + ch * 8 + 32);
      vr0 = *(const short8*)(vp + (size_t)r * st + ch * 8);
      vr1 = *(const short8*)(vp + (size_t)r * st + ch * 8 + 32);
    }
    if (t < 10) {   // tile t+1 masks
      const short* kp; const short* vp; const float* mp; int st;
      src_for(t + 1, kp, vp, mp, st);
#pragma unroll
      for (int i = 0; i < 4; ++i) m_nxt[i] = mp[4 * c + i];
    }

    // ---- QK^T ----
    short8 bk[4][2];
#pragma unroll
    for (int kt = 0; kt < 4; ++kt)
#pragma unroll
      for (int kc = 0; kc < 2; ++kc)
        bk[kt][kc] = *(const short8*)(&k_lds[cur][kt * 16 + c][kc * 32 + g * 8]);
    f32x4 sv[2][4];
#pragma unroll
    for (int mt = 0; mt < 2; ++mt)
#pragma unroll
      for (int kt = 0; kt < 4; ++kt) {
        f32x4 z = f32x4{0.f, 0.f, 0.f, 0.f};
        z = __builtin_amdgcn_mfma_f32_16x16x32_bf16(qa[mt][0], bk[kt][0], z, 0, 0, 0);
        z = __builtin_amdgcn_mfma_f32_16x16x32_bf16(qa[mt][1], bk[kt][1], z, 0, 0, 0);
        sv[mt][kt] = z;
      }
    // scale + mask, log2 domain (in place)
#pragma unroll
    for (int mt = 0; mt < 2; ++mt)
#pragma unroll
      for (int kt = 0; kt < 4; ++kt)
#pragma unroll
        for (int j = 0; j < 4; ++j)
          sv[mt][kt][j] = fmaf(sv[mt][kt][j], SCL2, m_cur[kt]);

    // ---- softmax pass 1 (optimistic, defer-max) ----
    float rs[2][4];
    float worst = 0.f;
#pragma unroll
    for (int mt = 0; mt < 2; ++mt)
#pragma unroll
      for (int j = 0; j < 4; ++j) {
        float mo = mrun[mt][j];
        float p0 = exp2g(sv[mt][0][j] - mo);
        float p1 = exp2g(sv[mt][1][j] - mo);
        float p2 = exp2g(sv[mt][2][j] - mo);
        float p3 = exp2g(sv[mt][3][j] - mo);
        float s01 = p0 + p1, s23 = p2 + p3;
        rs[mt][j] = s01 + s23;
        worst = fmaxf(worst, rs[mt][j]);
        unsigned w0 = cvt_pk_bf16(p0, p1);
        unsigned w1 = cvt_pk_bf16(p2, p3);
        int row = mt * 16 + 4 * g + j;
        unsigned bo = ((unsigned)row << 7) + ((unsigned)c << 3);
        bo ^= (unsigned)((row & 7) << 4);
        uint2 u; u.x = w0; u.y = w1;
        *(uint2*)(pbase + bo) = u;
      }

    if (__any(worst > 4096.f)) {   // rare: tile 0 + genuine max growth
#pragma unroll
      for (int mt = 0; mt < 2; ++mt)
#pragma unroll
        for (int j = 0; j < 4; ++j) {
          float v0 = sv[mt][0][j], v1 = sv[mt][1][j];
          float v2 = sv[mt][2][j], v3 = sv[mt][3][j];
          float tv = fmaxf(fmaxf(v0, v1), fmaxf(v2, v3));
          tv = fmaxf(tv, __shfl_xor(tv, 1));
          tv = fmaxf(tv, __shfl_xor(tv, 2));
          tv = fmaxf(tv, __shfl_xor(tv, 4));
          tv = fmaxf(tv, __shfl_xor(tv, 8));
          float mo = mrun[mt][j];
          float mn = fmaxf(mo, tv);
          float sc = exp2g(mo - mn);
#pragma unroll
          for (int dd = 0; dd < 4; ++dd) acc[mt][dd][j] *= sc;
          float p0 = exp2g(v0 - mn), p1 = exp2g(v1 - mn);
          float p2 = exp2g(v2 - mn), p3 = exp2g(v3 - mn);
          lrun[mt][j] = lrun[mt][j] * sc + ((p0 + p1) + (p2 + p3));
          mrun[mt][j] = mn;
          unsigned w0 = cvt_pk_bf16(p0, p1);
          unsigned w1 = cvt_pk_bf16(p2, p3);
          int row = mt * 16 + 4 * g + j;
          unsigned bo = ((unsigned)row << 7) + ((unsigned)c << 3);
          bo ^= (unsigned)((row & 7) << 4);
          uint2 u; u.x = w0; u.y = w1;
          *(uint2*)(pbase + bo) = u;
        }
    } else {
#pragma unroll
      for (int mt = 0; mt < 2; ++mt)
#pragma unroll
        for (int j = 0; j < 4; ++j) lrun[mt][j] += rs[mt][j];
    }

    // ---- PV ----
#pragma unroll
    for (int kk = 0; kk < 2; ++kk) {
      short8 pa[2];
#pragma unroll
      for (int mt = 0; mt < 2; ++mt) {
        int prow = mt * 16 + c;
        unsigned bo = ((unsigned)prow << 7) + (unsigned)(kk * 64 + g * 16);
        bo ^= (unsigned)((prow & 7) << 4);
        pa[mt] = *(const short8*)(pbase + bo);
      }
#pragma unroll
      for (int dd = 0; dd < 4; ++dd) {
        short8 bv = *(const short8*)(&v_lds[cur][dd * 16 + c][kk * 32 + g * 8]);
        acc[0][dd] = __builtin_amdgcn_mfma_f32_16x16x32_bf16(pa[0], bv, acc[0][dd], 0, 0, 0);
        acc[1][dd] = __builtin_amdgcn_mfma_f32_16x16x32_bf16(pa[1], bv, acc[1][dd], 0, 0, 0);
      }
    }
#pragma unroll
    for (int i = 0; i < 4; ++i) m_cur[i] = m_nxt[i];
  }

  // ---- epilogue ----
  float* ob = out + ((size_t)nh * 4096 + (size_t)b * 128 + (size_t)wid * 32) * 64;
#pragma unroll
  for (int mt = 0; mt < 2; ++mt)
#pragma unroll
    for (int j = 0; j < 4; ++j) {
      float l = lrun[mt][j];
      l += __shfl_xor(l, 1);
      l += __shfl_xor(l, 2);
      l += __shfl_xor(l, 4);
      l += __shfl_xor(l, 8);
      float inv = 1.f / l;
      int row = mt * 16 + g * 4 + j;
#pragma unroll
      for (int dd = 0; dd < 4; ++dd)
        ob[(size_t)row * 64 + dd * 16 + c] = acc[mt][dd][j] * inv;
    }
}

// ---------------- fallback (round-1 kernel, used if ws too small) -----------
__global__ __launch_bounds__(256) void lsg_attn_fb(
    const float* __restrict__ q_,  const float* __restrict__ k_,
    const float* __restrict__ v_,  const float* __restrict__ amask,
    const float* __restrict__ sk,  const float* __restrict__ sv,
    const float* __restrict__ smk, const float* __restrict__ gk,
    const float* __restrict__ gv,  const float* __restrict__ gmk,
    float* __restrict__ out) {
  constexpr int T = 4096, D = 64, TS = 1024;
  constexpr float NEGF = -3.402823466e38f;
  __shared__ __align__(16) short k_lds[32][72];
  __shared__ __align__(16) short v_lds[64][40];
  __shared__ __align__(16) short p_lds[4][32][40];
  __shared__ float m_lds[32];
  const int bid = blockIdx.x;
  const int b = bid & 31, nh = bid >> 5, n_ = nh / 12;
  const int tid = threadIdx.x, wid = tid >> 6, lane = tid & 63;
  const int c = lane & 15, g = lane >> 4;
  const float* qb = q_ + ((size_t)nh * T + (size_t)b * 128) * D;
  const float* kb = k_ + (size_t)nh * T * D;
  const float* vb = v_ + (size_t)nh * T * D;
  const float* skb = sk + (size_t)nh * TS * D;
  const float* svb = sv + (size_t)nh * TS * D;
  const float* gkb = gk + (size_t)nh * 64 * D;
  const float* gvb = gv + (size_t)nh * 64 * D;
  const float* am = amask + (size_t)n_ * T;
  const float* sm = smk + (size_t)n_ * TS;
  const float* gm = gmk + (size_t)n_ * 64;
  short8 qa[2][2];
#pragma unroll
  for (int mt = 0; mt < 2; ++mt)
#pragma unroll
    for (int kc = 0; kc < 2; ++kc) {
      const float* qp = qb + (size_t)(wid * 32 + mt * 16 + c) * D + kc * 32 + g * 8;
      short8 t;
#pragma unroll
      for (int j = 0; j < 8; ++j) t[j] = f2bf(qp[j]);
      qa[mt][kc] = t;
    }
  f32x4 acc[2][4];
#pragma unroll
  for (int mt = 0; mt < 2; ++mt)
#pragma unroll
    for (int dd = 0; dd < 4; ++dd) acc[mt][dd] = f32x4{0.f, 0.f, 0.f, 0.f};
  float mrun[2][4], lrun[2][4];
#pragma unroll
  for (int mt = 0; mt < 2; ++mt)
#pragma unroll
    for (int j = 0; j < 4; ++j) { mrun[mt][j] = NEGF; lrun[mt][j] = 0.f; }
  const int key_local = tid >> 3;
  const int seg = tid & 7;
  const int d0 = seg * 8;
  for (int tile = 0; tile < 22; ++tile) {
    __syncthreads();
    {
      const int kk = tile * 32 + key_local;
      const float* ksrc; const float* vsrc; float mval; bool valid;
      if (kk < 64) {
        ksrc = gkb + kk * D; vsrc = gvb + kk * D; mval = gm[kk]; valid = true;
      } else if (kk < 320) {
        int s = b * 32 - 160 + (kk - 64) + ((kk >= 192) ? 96 : 0);
        valid = (s >= 0) && (s < TS);
        int sc2 = valid ? s : 0;
        ksrc = skb + sc2 * D; vsrc = svb + sc2 * D;
        mval = valid ? sm[sc2] : NEGF;
      } else {
        int tt = b * 128 - 128 + (kk - 320);
        valid = (tt >= 0) && (tt < T);
        int tc = valid ? tt : 0;
        ksrc = kb + tc * D; vsrc = vb + tc * D;
        mval = valid ? am[tc] : NEGF;
      }
      short8 k8; short v8[8];
      if (valid) {
#pragma unroll
        for (int j = 0; j < 8; ++j) { k8[j] = f2bf(ksrc[d0 + j]); v8[j] = f2bf(vsrc[d0 + j]); }
      } else {
#pragma unroll
        for (int j = 0; j < 8; ++j) { k8[j] = 0; v8[j] = 0; }
      }
      *(short8*)(&k_lds[key_local][d0]) = k8;
#pragma unroll
      for (int j = 0; j < 8; ++j) v_lds[d0 + j][key_local] = v8[j];
      if (seg == 0) m_lds[key_local] = mval;
    }
    __syncthreads();
    short8 bk[2][2];
#pragma unroll
    for (int kt = 0; kt < 2; ++kt)
#pragma unroll
      for (int kc = 0; kc < 2; ++kc)
        bk[kt][kc] = *(const short8*)(&k_lds[kt * 16 + c][kc * 32 + g * 8]);
    f32x4 s_[2][2];
#pragma unroll
    for (int mt = 0; mt < 2; ++mt)
#pragma unroll
      for (int kt = 0; kt < 2; ++kt) {
        f32x4 z = f32x4{0.f, 0.f, 0.f, 0.f};
        z = __builtin_amdgcn_mfma_f32_16x16x32_bf16(qa[mt][0], bk[kt][0], z, 0, 0, 0);
        z = __builtin_amdgcn_mfma_f32_16x16x32_bf16(qa[mt][1], bk[kt][1], z, 0, 0, 0);
        s_[mt][kt] = z;
      }
    const float msk0 = m_lds[c];
    const float msk1 = m_lds[16 + c];
#pragma unroll
    for (int mt = 0; mt < 2; ++mt) {
#pragma unroll
      for (int j = 0; j < 4; ++j) {
        float s0 = s_[mt][0][j] * 0.125f + msk0;
        float s1 = s_[mt][1][j] * 0.125f + msk1;
        float tv = fmaxf(s0, s1);
        tv = fmaxf(tv, __shfl_xor(tv, 1));
        tv = fmaxf(tv, __shfl_xor(tv, 2));
        tv = fmaxf(tv, __shfl_xor(tv, 4));
        tv = fmaxf(tv, __shfl_xor(tv, 8));
        float mold = mrun[mt][j];
        float mnew = fmaxf(mold, tv);
        float scale = __expf(mold - mnew);
        mrun[mt][j] = mnew;
        float p0 = __expf(s0 - mnew);
        float p1 = __expf(s1 - mnew);
        lrun[mt][j] = lrun[mt][j] * scale + p0 + p1;
#pragma unroll
        for (int dd = 0; dd < 4; ++dd) acc[mt][dd][j] *= scale;
        p_lds[wid][mt * 16 + g * 4 + j][c] = f2bf(p0);
        p_lds[wid][mt * 16 + g * 4 + j][16 + c] = f2bf(p1);
      }
    }
    __syncthreads();
#pragma unroll
    for (int mt = 0; mt < 2; ++mt) {
      short8 pa = *(const short8*)(&p_lds[wid][mt * 16 + c][g * 8]);
#pragma unroll
      for (int dd = 0; dd < 4; ++dd) {
        short8 bv = *(const short8*)(&v_lds[dd * 16 + c][g * 8]);
        acc[mt][dd] = __builtin_amdgcn_mfma_f32_16x16x32_bf16(pa, bv, acc[mt][dd], 0, 0, 0);
      }
    }
  }
  float* ob = out + ((size_t)nh * T + (size_t)b * 128 + (size_t)wid * 32) * D;
#pragma unroll
  for (int mt = 0; mt < 2; ++mt)
#pragma unroll
    for (int j = 0; j < 4; ++j) {
      float l = lrun[mt][j];
      l += __shfl_xor(l, 1);
      l += __shfl_xor(l, 2);
      l += __shfl_xor(l, 4);
      l += __shfl_xor(l, 8);
      float inv = 1.f / l;
      int row = mt * 16 + g * 4 + j;
#pragma unroll
      for (int dd = 0; dd < 4; ++dd)
        ob[(size_t)row * D + dd * 16 + c] = acc[mt][dd][j] * inv;
    }
}

extern "C" void kernel_launch(void* const* d_in, const int* in_sizes, int n_in,
                              void* d_out, int out_size, void* d_ws, size_t ws_size,
                              hipStream_t stream) {
  const float* q  = (const float*)d_in[0];
  const float* k  = (const float*)d_in[1];
  const float* v  = (const float*)d_in[2];
  const float* am = (const float*)d_in[3];
  const float* sk = (const float*)d_in[4];
  const float* sv = (const float*)d_in[5];
  const float* sm = (const float*)d_in[6];
  const float* gk = (const float*)d_in[7];
  const float* gv = (const float*)d_in[8];
  const float* gm = (const float*)d_in[9];
  float* out = (float*)d_out;

  size_t off = 0;
  char* base = (char*)d_ws;
  auto alloc = [&](size_t bytes) { void* p = base + off; off += bytes; return p; };
  short* KL  = (short*)alloc(13369344);  // [24][4352][64] bf16
  short* VTL = (short*)alloc(13369344);  // [24][64][4352]
  short* KS  = (short*)alloc(4128768);   // [24][1344][64]
  short* VTS = (short*)alloc(4128768);   // [24][64][1344]
  short* KG  = (short*)alloc(196608);    // [24][64][64]
  short* VTG = (short*)alloc(196608);    // [24][64][64]
  float* AM2 = (float*)alloc(34816);     // [2][4352]
  float* SM2 = (float*)alloc(10752);     // [2][1344]
  float* GM2 = (float*)alloc(512);       // [2][64]

  if (off <= ws_size) {
    hipLaunchKernelGGL(convk_kernel, dim3(3264), dim3(256), 0, stream, k,  KL, 4096, 128, 24 * 4352 * 8);
    hipLaunchKernelGGL(convk_kernel, dim3(1008), dim3(256), 0, stream, sk, KS, 1024, 160, 24 * 1344 * 8);
    hipLaunchKernelGGL(convk_kernel, dim3(48),   dim3(256), 0, stream, gk, KG, 64,   0,   24 * 64 * 8);
    hipLaunchKernelGGL(transv_kernel, dim3(24 * 68), dim3(256), 0, stream, v,  VTL, 4096, 128, 68);
    hipLaunchKernelGGL(transv_kernel, dim3(24 * 21), dim3(256), 0, stream, sv, VTS, 1024, 160, 21);
    hipLaunchKernelGGL(transv_kernel, dim3(24),      dim3(256), 0, stream, gv, VTG, 64,   0,   1);
    hipLaunchKernelGGL(maskk_kernel, dim3(45), dim3(256), 0, stream, am, sm, gm, AM2, SM2, GM2);
    hipLaunchKernelGGL(lsg_attn2, dim3(768), dim3(256), 0, stream,
                       KL, VTL, KS, VTS, KG, VTG, AM2, SM2, GM2, q, out);
  } else {
    hipLaunchKernelGGL(lsg_attn_fb, dim3(768), dim3(256), 0, stream,
                       q, k, v, am, sk, sv, sm, gk, gv, gm, out);
  }
}